// Round 3
// baseline (40.553 us; speedup 1.0000x reference)
//
#include <hip/hip_runtime.h>

#define HWOUT 50176   // 224*224
#define GRID  256     // blocks; <= #CUs so all blocks co-resident (spin barrier safe)
#define CHUNK 2048    // rows staged per block-iteration (1024 thr * 2 rows)
#define OUTPB 196     // outputs per block = HWOUT/GRID

typedef __attribute__((ext_vector_type(8))) short short8;
typedef __attribute__((ext_vector_type(4))) float f32x4;

__device__ __forceinline__ float fast_sigmoid(float x) {
    float t = __builtin_amdgcn_exp2f(-1.44269504088896340736f * x);
    return __builtin_amdgcn_rcpf(1.0f + t);
}
__device__ __forceinline__ float silu_f(float x) { return x * fast_sigmoid(x); }

__device__ __forceinline__ short to_bf16_bits(float f) {
    unsigned u = __builtin_bit_cast(unsigned, f);
    u += 0x7FFFu + ((u >> 16) & 1u);   // round-to-nearest-even
    return (short)(u >> 16);
}

// One kernel does: stage1 (silu->W1->silu->partial sums) -> device barrier ->
// redundant small reduce -> W2 matvec -> silu -> clamp -> out.
__global__ __launch_bounds__(1024, 4) void k_fused(
        const float* __restrict__ x,  const float* __restrict__ W1,
        const float* __restrict__ b1, const float* __restrict__ W2,
        const float* __restrict__ b2, float* __restrict__ out,
        float* __restrict__ ws, int N, float invN) {
    __shared__ short xs[CHUNK * 8];     // 32 KB bf16 rows (7 padded to 8)
    __shared__ float red[16][64];       // 4 KB
    __shared__ float msh[64];
    __shared__ float osum[4][256];      // 4 KB

    unsigned* ctr = (unsigned*)ws;          // zeroed by memset node each launch
    float* partial = ws + 64;               // GRID*64 floats

    const int t    = threadIdx.x;
    const int lane = t & 63;
    const int wave = t >> 6;
    const int b    = blockIdx.x;

    // ---- B fragments: bf[g][j] = W1pad[8*(lane>>4)+j][g*16+(lane&15)], k>=7 -> 0
    const int krow = (lane >> 4) * 8;
    const int c    = lane & 15;
    short8 bf[4];
    float  bcol[4];
#pragma unroll
    for (int g = 0; g < 4; ++g) {
#pragma unroll
        for (int j = 0; j < 8; ++j) {
            int k = krow + j;
            float v = (k < 7) ? W1[k * 64 + g * 16 + c] : 0.0f;
            bf[g][j] = to_bf16_bits(v);
        }
        bcol[g] = b1[g * 16 + c];
    }

    float accf[4] = {0.0f, 0.0f, 0.0f, 0.0f};
    const int nch = (N + CHUNK - 1) / CHUNK;
    const short8 zero8 = {0, 0, 0, 0, 0, 0, 0, 0};
    const f32x4  zero4 = {0.0f, 0.0f, 0.0f, 0.0f};

    for (int ch = b; ch < nch; ch += GRID) {
        __syncthreads();                    // prior tile reads done
        {   // stage 2 rows per thread, float2-vectorized (56B per thread, 8-aligned)
            const int r0 = ch * CHUNK + 2 * t;
            float v[14];
            if (r0 + 1 < N) {
                const float2* p = reinterpret_cast<const float2*>(x + (size_t)r0 * 7);
#pragma unroll
                for (int i = 0; i < 7; ++i) { float2 q = p[i]; v[2*i] = q.x; v[2*i+1] = q.y; }
            } else {
                const long total = (long)N * 7;
#pragma unroll
                for (int i = 0; i < 14; ++i) {
                    long idx = (long)r0 * 7 + i;
                    v[i] = (idx < total) ? x[idx] : 0.0f;
                }
            }
            short8 p0, p1;
#pragma unroll
            for (int k = 0; k < 7; ++k) {
                p0[k] = to_bf16_bits(silu_f(v[k]));
                p1[k] = to_bf16_bits(silu_f(v[7 + k]));
            }
            p0[7] = 0; p1[7] = 0;
            *reinterpret_cast<short8*>(&xs[(2 * t + 0) * 8]) = p0;
            *reinterpret_cast<short8*>(&xs[(2 * t + 1) * 8]) = p1;
        }
        __syncthreads();

        const bool full = (ch * CHUNK + CHUNK <= N);
#pragma unroll
        for (int tt = 0; tt < 8; ++tt) {
            const int tile = wave * 8 + tt;         // wave owns rows [wave*128, +128)
            short8 av = *reinterpret_cast<short8*>(&xs[(tile * 16 + c) * 8]);
            av = (lane < 16) ? av : zero8;          // lanes>=16 are K-pad
#pragma unroll
            for (int g = 0; g < 4; ++g) {
                f32x4 d = __builtin_amdgcn_mfma_f32_16x16x32_bf16(av, bf[g], zero4, 0, 0, 0);
                if (full) {
#pragma unroll
                    for (int r = 0; r < 4; ++r) accf[g] += silu_f(d[r] + bcol[g]);
                } else {
                    const int r0g = ch * CHUNK + tile * 16 + (lane >> 4) * 4;
#pragma unroll
                    for (int r = 0; r < 4; ++r) {
                        float s = silu_f(d[r] + bcol[g]);
                        accf[g] += (r0g + r < N) ? s : 0.0f;
                    }
                }
            }
        }
    }

    // ---- collapse rows within wave (C rows live in lane>>4 groups), then across waves
#pragma unroll
    for (int g = 0; g < 4; ++g) {
        accf[g] += __shfl_xor(accf[g], 16, 64);
        accf[g] += __shfl_xor(accf[g], 32, 64);
    }
    __syncthreads();
    if (lane < 16) {
#pragma unroll
        for (int g = 0; g < 4; ++g) red[wave][g * 16 + lane] = accf[g];
    }
    __syncthreads();
    if (t < 64) {
        float s = 0.0f;
#pragma unroll
        for (int wv = 0; wv < 16; ++wv) s += red[wv][t];
        partial[b * 64 + t] = s;
    }

    // ---- device-scope barrier (all GRID blocks co-resident by construction)
    __syncthreads();                       // partial stores drained (vmcnt 0)
    if (t == 0) {
        __threadfence();                   // release: flush to device-coherent point
        atomicAdd(ctr, 1u);
        while (__hip_atomic_load(ctr, __ATOMIC_RELAXED, __HIP_MEMORY_SCOPE_AGENT)
               < (unsigned)gridDim.x) {
            __builtin_amdgcn_s_sleep(4);
        }
        __threadfence();                   // acquire: invalidate L1/L2
    }
    __syncthreads();

    // ---- redundant reduce partial[GRID][64] -> msh[64]
    {
        const int cc = t & 63, seg = t >> 6;        // 16 segments
        float s = 0.0f;
#pragma unroll 4
        for (int r = seg; r < GRID; r += 16) s += partial[r * 64 + cc];
        red[seg][cc] = s;
    }
    __syncthreads();
    if (t < 64) {
        float s = 0.0f;
#pragma unroll
        for (int sg = 0; sg < 16; ++sg) s += red[sg][t];
        msh[t] = s * invN;
    }
    __syncthreads();

    // ---- output: 196 outputs per block, 4-way k-split across the 1024 threads
    {
        const int s = t >> 8;              // 0..3 -> k in [16s, 16s+16)
        const int i = t & 255;
        float acc = 0.0f;
        if (i < OUTPB) {
            const int j = b * OUTPB + i;
#pragma unroll
            for (int k = 0; k < 16; ++k)
                acc = fmaf(msh[s * 16 + k], W2[(size_t)(s * 16 + k) * HWOUT + j], acc);
        }
        osum[s][i] = acc;
    }
    __syncthreads();
    if (t < OUTPB) {
        const int j = b * OUTPB + t;
        float e = osum[0][t] + osum[1][t] + osum[2][t] + osum[3][t] + b2[j];
        e = silu_f(e);
        out[j] = fminf(fmaxf(e, 0.0f), 1.0f);
    }
}

extern "C" void kernel_launch(void* const* d_in, const int* in_sizes, int n_in,
                              void* d_out, int out_size, void* d_ws, size_t ws_size,
                              hipStream_t stream) {
    const float* x  = (const float*)d_in[0];
    const float* W1 = (const float*)d_in[1];
    const float* b1 = (const float*)d_in[2];
    const float* W2 = (const float*)d_in[3];
    const float* b2 = (const float*)d_in[4];
    float* out = (float*)d_out;

    const int N = in_sizes[0] / 7;

    // ws layout: [0..63] barrier counter (+pad), [64 ..] partial[GRID][64]
    hipMemsetAsync(d_ws, 0, 64 * sizeof(float), stream);   // graph memset node
    k_fused<<<GRID, 1024, 0, stream>>>(x, W1, b1, W2, b2, out,
                                       (float*)d_ws, N, 1.0f / (float)N);
}

// Round 4
// 34.043 us; speedup vs baseline: 1.1912x; 1.1912x over previous
//
#include <hip/hip_runtime.h>

#define HWOUT 50176   // 224*224
#define NBLK  1024    // stage1 grid size == rows of partial[]
#define CHUNK 256     // rows staged per block iteration

typedef __attribute__((ext_vector_type(8))) short short8;
typedef __attribute__((ext_vector_type(4))) float f32x4;

__device__ __forceinline__ float fast_sigmoid(float x) {
    float t = __builtin_amdgcn_exp2f(-1.44269504088896340736f * x);
    return __builtin_amdgcn_rcpf(1.0f + t);
}
__device__ __forceinline__ float silu_f(float x) { return x * fast_sigmoid(x); }

__device__ __forceinline__ short to_bf16_bits(float f) {
    unsigned u = __builtin_bit_cast(unsigned, f);
    u += 0x7FFFu + ((u >> 16) & 1u);   // round-to-nearest-even
    return (short)(u >> 16);
}

// ---------------- Stage 1: partial[b][c] = sum over block's rows of
//                  silu( silu(x_row) . W1[:,c] + b1[c] )
// MFMA 16x16x32 bf16. Bias enters via the MFMA C operand.
__global__ __launch_bounds__(256) void k_stage1(const float* __restrict__ x,
                                                const float* __restrict__ W1,
                                                const float* __restrict__ b1,
                                                float* __restrict__ partial,
                                                int N) {
    __shared__ float rawf[CHUNK * 7];   // 7 KB raw f32 chunk
    __shared__ short xs[CHUNK * 8];     // 4 KB bf16 rows (7 padded to 8)
    __shared__ float red[4][64];
    const int t = threadIdx.x;
    const int lane = t & 63;
    const int wave = t >> 6;

    // B fragments: bf[g][j] = W1pad[8*(lane>>4)+j][g*16+(lane&15)], k>=7 -> 0
    const int krow = (lane >> 4) * 8;
    const int c = lane & 15;
    short8 bf[4];
    f32x4 bias4[4];
#pragma unroll
    for (int g = 0; g < 4; ++g) {
#pragma unroll
        for (int j = 0; j < 8; ++j) {
            int k = krow + j;
            float v = (k < 7) ? W1[k * 64 + g * 16 + c] : 0.0f;
            bf[g][j] = to_bf16_bits(v);
        }
        float bb = b1[g * 16 + c];
        bias4[g] = (f32x4){bb, bb, bb, bb};
    }

    float accf[4] = {0.0f, 0.0f, 0.0f, 0.0f};
    const int nchunk = (N + CHUNK - 1) / CHUNK;
    const long totalF = (long)N * 7;
    const short8 zero8 = {0, 0, 0, 0, 0, 0, 0, 0};
    const float4* gx4 = reinterpret_cast<const float4*>(x);

    for (int ch = blockIdx.x; ch < nchunk; ch += NBLK) {
        __syncthreads();                  // prior tile reads done before overwrite
        // ---- coalesced raw staging: 448 float4 per chunk (CHUNK*7/4)
        {
            const long f4base = (long)ch * (CHUNK * 7 / 4);
#pragma unroll
            for (int s = 0; s < 2; ++s) {
                int i = s * 256 + t;
                if (i < CHUNK * 7 / 4) {
                    long gi = f4base + i;
                    float4 v;
                    if ((gi + 1) * 4 <= totalF) {
                        v = gx4[gi];
                    } else {
                        float tmp[4];
#pragma unroll
                        for (int e = 0; e < 4; ++e) {
                            long fi = gi * 4 + e;
                            tmp[e] = (fi < totalF) ? x[fi] : 0.0f;
                        }
                        v = (float4){tmp[0], tmp[1], tmp[2], tmp[3]};
                    }
                    *reinterpret_cast<float4*>(&rawf[i * 4]) = v;
                }
            }
        }
        __syncthreads();
        // ---- convert: thread t owns row t of the chunk
        {
            short8 p;
#pragma unroll
            for (int k = 0; k < 7; ++k)
                p[k] = to_bf16_bits(silu_f(rawf[t * 7 + k]));
            p[7] = 0;
            *reinterpret_cast<short8*>(&xs[t * 8]) = p;
        }
        __syncthreads();

        const bool full = (ch * CHUNK + CHUNK <= N);
        const int chbase = ch * CHUNK;
#pragma unroll
        for (int tt = 0; tt < 4; ++tt) {
            const int tile = wave * 4 + tt;
            short8 av = *reinterpret_cast<short8*>(&xs[(tile * 16 + c) * 8]);
            av = (lane < 16) ? av : zero8;    // lanes>=16 are K-pad
#pragma unroll
            for (int g = 0; g < 4; ++g) {
                f32x4 d = __builtin_amdgcn_mfma_f32_16x16x32_bf16(av, bf[g], bias4[g], 0, 0, 0);
                if (full) {
#pragma unroll
                    for (int r = 0; r < 4; ++r) accf[g] += silu_f(d[r]);
                } else {
                    const int r0 = chbase + tile * 16 + (lane >> 4) * 4;
#pragma unroll
                    for (int r = 0; r < 4; ++r) {
                        float s = silu_f(d[r]);
                        accf[g] += (r0 + r < N) ? s : 0.0f;
                    }
                }
            }
        }
    }

    // C layout: col = g*16 + (lane&15), rows split across lane>>4 -> xor-reduce
#pragma unroll
    for (int g = 0; g < 4; ++g) {
        accf[g] += __shfl_xor(accf[g], 16, 64);
        accf[g] += __shfl_xor(accf[g], 32, 64);
    }
    if (lane < 16) {
#pragma unroll
        for (int g = 0; g < 4; ++g) red[wave][g * 16 + lane] = accf[g];
    }
    __syncthreads();
    if (t < 64)
        partial[blockIdx.x * 64 + t] = red[0][t] + red[1][t] + red[2][t] + red[3][t];
}

// ---------------- Stage 2 (fused): every block redundantly reduces
// partial[NBLK][64] -> m[64] (L2-resident per XCD), then computes its 256
// outputs of clamp(silu(m @ W2 + b2), 0, 1).
__global__ __launch_bounds__(256) void k_out2(const float* __restrict__ partial,
                                              const float* __restrict__ W2,
                                              const float* __restrict__ b2,
                                              float* __restrict__ out,
                                              float invN) {
    __shared__ float4 red[256];
    __shared__ float ml[64];
    const int t = threadIdx.x;
    const int c4 = t & 15;     // float4 column group (cols 4*c4 .. 4*c4+3)
    const int grp = t >> 4;    // 0..15
    const float4* p4 = reinterpret_cast<const float4*>(partial);

    float4 s = {0.0f, 0.0f, 0.0f, 0.0f};
#pragma unroll 8
    for (int r = grp; r < NBLK; r += 16) {   // 64 coalesced float4 loads
        float4 v = p4[r * 16 + c4];
        s.x += v.x; s.y += v.y; s.z += v.z; s.w += v.w;
    }
    red[t] = s;
    __syncthreads();
    if (t < 16) {
        float4 a = {0.0f, 0.0f, 0.0f, 0.0f};
#pragma unroll
        for (int g = 0; g < 16; ++g) {
            float4 v = red[g * 16 + t];
            a.x += v.x; a.y += v.y; a.z += v.z; a.w += v.w;
        }
        ml[4 * t + 0] = a.x * invN;
        ml[4 * t + 1] = a.y * invN;
        ml[4 * t + 2] = a.z * invN;
        ml[4 * t + 3] = a.w * invN;
    }
    __syncthreads();

    const int j = blockIdx.x * 256 + t;   // grid is exactly HWOUT/256
    float acc = b2[j];
#pragma unroll
    for (int k4 = 0; k4 < 16; ++k4) {
        float4 mv = *reinterpret_cast<float4*>(&ml[k4 * 4]);
        acc = fmaf(mv.x, W2[(size_t)(k4 * 4 + 0) * HWOUT + j], acc);
        acc = fmaf(mv.y, W2[(size_t)(k4 * 4 + 1) * HWOUT + j], acc);
        acc = fmaf(mv.z, W2[(size_t)(k4 * 4 + 2) * HWOUT + j], acc);
        acc = fmaf(mv.w, W2[(size_t)(k4 * 4 + 3) * HWOUT + j], acc);
    }
    float e = silu_f(acc);
    out[j] = fminf(fmaxf(e, 0.0f), 1.0f);
}

extern "C" void kernel_launch(void* const* d_in, const int* in_sizes, int n_in,
                              void* d_out, int out_size, void* d_ws, size_t ws_size,
                              hipStream_t stream) {
    const float* x  = (const float*)d_in[0];
    const float* W1 = (const float*)d_in[1];
    const float* b1 = (const float*)d_in[2];
    const float* W2 = (const float*)d_in[3];
    const float* b2 = (const float*)d_in[4];
    float* out = (float*)d_out;

    const int N = in_sizes[0] / 7;
    float* partial = (float*)d_ws;   // NBLK*64 floats

    k_stage1<<<NBLK, 256, 0, stream>>>(x, W1, b1, partial, N);
    k_out2<<<HWOUT / 256, 256, 0, stream>>>(partial, W2, b2, out, 1.0f / (float)N);
}